// Round 18
// baseline (533.318 us; speedup 1.0000x reference)
//
#include <hip/hip_runtime.h>
#include <hip/hip_bf16.h>
#include <stdint.h>
#include <math.h>

typedef __attribute__((ext_vector_type(8))) short bf16x8;
typedef __attribute__((ext_vector_type(4))) float f32x4;

#define D_K 256
#define JCHUNK 2048
#define SB 256              // superblock j-width (phase alternation unit)
#define NSB (JCHUNK / SB)   // 8
#define BT 32               // MFMA subtile j-width (staged tile rows)
#define NST (SB / BT)       // 8 subtiles per superblock

__device__ __forceinline__ unsigned short f2bf(float f) {
    unsigned u = __float_as_uint(f);
    u += 0x7fffu + ((u >> 16) & 1u);   // round-to-nearest-even
    return (unsigned short)(u >> 16);
}
__device__ __forceinline__ float bf2f(unsigned short u) {
    return __uint_as_float(((unsigned)u) << 16);
}
__device__ __forceinline__ void gload_lds16(const void* g, void* l) {
    __builtin_amdgcn_global_load_lds(
        (const __attribute__((address_space(1))) void*)g,
        (__attribute__((address_space(3))) void*)l,
        16, 0, 0);
}

// ---------------- Kernel 1: row-normalize z -> bf16; zero partials ----------------
__global__ void normalize_k(const float* __restrict__ z,
                            unsigned short* __restrict__ zn,
                            float* __restrict__ part, int N) {
    int gid  = blockIdx.x * blockDim.x + threadIdx.x;
    if (gid < 5 * N) part[gid] = 0.f;      // stream-ordered before fused_k
    int gw   = gid >> 6;                   // one wave per row
    int lane = threadIdx.x & 63;
    if (gw >= N) return;
    float4 v = reinterpret_cast<const float4*>(z + (size_t)gw * D_K)[lane];
    float ss = v.x * v.x + v.y * v.y + v.z * v.z + v.w * v.w;
#pragma unroll
    for (int m = 32; m; m >>= 1) ss += __shfl_xor(ss, m);
    float sc = 1.0f / fmaxf(sqrtf(ss), 1e-8f);
    ushort4 o;
    o.x = f2bf(v.x * sc); o.y = f2bf(v.y * sc);
    o.z = f2bf(v.z * sc); o.w = f2bf(v.w * sc);
    reinterpret_cast<ushort4*>(zn + (size_t)gw * D_K)[lane] = o;
}

// Stage one 32-row x 256-d bf16 zn tile (16 KB) into LDS in [kslot][row][16B]
__device__ __forceinline__ void stage_zn(char* dst, const unsigned short* zn,
                                         int j0, int tid, int wid) {
#pragma unroll
    for (int it = 0; it < 4; ++it) {
        int li    = it * 4096 + tid * 16;
        int kslot = li >> 9;          // 0..31
        int row   = (li >> 4) & 31;   // 0..31
        const char* src = reinterpret_cast<const char*>(zn) +
                          ((size_t)(j0 + row) << 9) + (size_t)kslot * 16;
        gload_lds16(src, dst + it * 4096 + wid * 1024);
    }
}

// ---------------- Kernel 2: two-phase fused kernel (R17 exact, best) ----------------
__global__ __launch_bounds__(256, 2) void fused_k(
    const unsigned short* __restrict__ zn,
    const float* __restrict__ adj,
    const float* __restrict__ tsim,
    float* __restrict__ part, int N) {
    __shared__ alignas(128) char stageL[2][BT * 512];   // 2 x 16 KB
    __shared__ alignas(128) char parkL[4][16 * 512];    // 4 waves x 8 KB bf16 park

    const float INV_T = 1.0f / 0.07f;
    const int NIB = N >> 6;
    int ib  = (blockIdx.x >> 2) & (NIB - 1);   // slow-varying
    int jc  = blockIdx.x & 3;                  // fast-varying
    int sb0 = ib & (NSB - 1);                  // per-block superblock rotation
    int tid = threadIdx.x;
    int wid = tid >> 6, lane = tid & 63;
    int l15 = lane & 15, lhi = lane >> 4;
    int i0w = ib * 64 + wid * 16;
    int gi  = i0w + l15;
    int jb  = jc * JCHUNK;
    char* parkW = parkL[wid];

    bf16x8 bfr[8];
    {
        const bf16x8* bp = reinterpret_cast<const bf16x8*>(zn + (size_t)gi * D_K) + lhi;
#pragma unroll
        for (int ks = 0; ks < 8; ++ks) bfr[ks] = bp[ks * 4];
    }

    float accden = 0.f;
    float s1p[4] = {0.f, 0.f, 0.f, 0.f};
    float app[4] = {0.f, 0.f, 0.f, 0.f};
    float t1p[4] = {0.f, 0.f, 0.f, 0.f};
    float ttp[4] = {0.f, 0.f, 0.f, 0.f};

    stage_zn(stageL[0], zn, jb + sb0 * SB, tid, wid);
    asm volatile("s_waitcnt vmcnt(0)" ::: "memory");
    __syncthreads();
    int cur = 0;

    for (int s = 0; s < NSB; ++s) {
        int sbi = (sb0 + s) & (NSB - 1);
        int jsb = jb + sbi * SB;

        for (int st = 0; st < NST; ++st) {
            if (st + 1 < NST) {
                stage_zn(stageL[cur ^ 1], zn, jsb + (st + 1) * BT, tid, wid);
            } else if (s + 1 < NSB) {
                int nsb = (sb0 + s + 1) & (NSB - 1);
                stage_zn(stageL[cur ^ 1], zn, jb + nsb * SB, tid, wid);
            }

            const char* buf = stageL[cur];
            f32x4 acc[2] = {(f32x4){0.f,0.f,0.f,0.f}, (f32x4){0.f,0.f,0.f,0.f}};
#pragma unroll
            for (int ks = 0; ks < 8; ++ks) {
#pragma unroll
                for (int t = 0; t < 2; ++t) {
                    int boff = (ks << 11) + (lhi << 9) + (t << 8) + (l15 << 4);
                    bf16x8 aj = *reinterpret_cast<const bf16x8*>(buf + boff);
                    acc[t] = __builtin_amdgcn_mfma_f32_16x16x32_bf16(aj, bfr[ks], acc[t], 0, 0, 0);
                }
            }
#pragma unroll
            for (int t = 0; t < 2; ++t) {
                int jcol = st * BT + t * 16 + lhi * 4;
                float sv[4];
#pragma unroll
                for (int r = 0; r < 4; ++r) {
                    sv[r] = acc[t][r] * INV_T;
                    accden += (gi == jsb + jcol + r) ? 0.f : __expf(sv[r]);
                }
                ushort4 pk;
                pk.x = f2bf(sv[0]); pk.y = f2bf(sv[1]);
                pk.z = f2bf(sv[2]); pk.w = f2bf(sv[3]);
                *reinterpret_cast<ushort4*>(
                    parkW + l15 * 512 + ((jcol * 2) ^ ((l15 & 7) << 4))) = pk;
            }
            asm volatile("s_waitcnt vmcnt(0)" ::: "memory");
            __syncthreads();
            cur ^= 1;
        }

#pragma unroll
        for (int rg = 0; rg < 4; ++rg) {
            int irow = rg * 4 + lhi;
            const float* ar = adj  + (size_t)(i0w + irow) * N + jsb + l15 * 8;
            const float* tr = tsim + (size_t)(i0w + irow) * N + jsb + l15 * 8;
            const char*  pr = parkW + irow * 512;
            int sx = (irow & 7) << 4;
#pragma unroll
            for (int q = 0; q < 2; ++q) {
                f32x4 a0 = __builtin_nontemporal_load(
                    reinterpret_cast<const f32x4*>(ar + q * 128));
                f32x4 a1 = __builtin_nontemporal_load(
                    reinterpret_cast<const f32x4*>(ar + q * 128 + 4));
                f32x4 t0 = __builtin_nontemporal_load(
                    reinterpret_cast<const f32x4*>(tr + q * 128));
                f32x4 t1 = __builtin_nontemporal_load(
                    reinterpret_cast<const f32x4*>(tr + q * 128 + 4));
                bf16x8 s8 = *reinterpret_cast<const bf16x8*>(
                    pr + ((l15 * 16 + q * 256) ^ sx));
                float s[8];
#pragma unroll
                for (int e = 0; e < 8; ++e) s[e] = bf2f((unsigned short)s8[e]);
                float s1 = s1p[rg], t1v = t1p[rg];
#pragma unroll
                for (int e = 0; e < 4; ++e) {
                    s1  = fmaf(a0[e], s[e], s1);
                    s1  = fmaf(a1[e], s[4 + e], s1);
                    t1v = fmaf(t0[e], s[e], t1v);
                    t1v = fmaf(t1[e], s[4 + e], t1v);
                }
                s1p[rg] = s1; t1p[rg] = t1v;
                app[rg] += (a0[0] + a0[1] + a0[2] + a0[3]) +
                           (a1[0] + a1[1] + a1[2] + a1[3]);
                ttp[rg] += (t0[0] + t0[1] + t0[2] + t0[3]) +
                           (t1[0] + t1[1] + t1[2] + t1[3]);
            }
        }
    }

    accden += __shfl_xor(accden, 16); accden += __shfl_xor(accden, 32);
    if (lhi == 0) atomicAdd(part + gi, accden);
#pragma unroll
    for (int rg = 0; rg < 4; ++rg) {
        float s = s1p[rg], a = app[rg], u = t1p[rg], w = ttp[rg];
#pragma unroll
        for (int m = 1; m < 16; m <<= 1) {
            s += __shfl_xor(s, m); a += __shfl_xor(a, m);
            u += __shfl_xor(u, m); w += __shfl_xor(w, m);
        }
        if (l15 == 0) {
            int gr = i0w + rg * 4 + lhi;
            atomicAdd(part + (size_t)N + gr, s);
            atomicAdd(part + (size_t)2 * N + gr, a);
            atomicAdd(part + (size_t)3 * N + gr, u);
            atomicAdd(part + (size_t)4 * N + gr, w);
        }
    }
}

// ---------------- Kernel 3: finalize scalar ----------------
__global__ void finalize_k(const float* __restrict__ part, float* __restrict__ out, int N) {
    const float* den = part;
    const float* s1  = part + (size_t)N;
    const float* aa  = part + (size_t)2 * N;
    const float* t1  = part + (size_t)3 * N;
    const float* tt  = part + (size_t)4 * N;
    float acc = 0.f;
    for (int i = threadIdx.x; i < N; i += blockDim.x) {
        float ld = logf(den[i] + 1e-8f);
        acc += -(s1[i] - ld * aa[i]) / (aa[i] + 1e-8f)
               - (t1[i] - ld * tt[i]) / (tt[i] + 1e-8f);
    }
#pragma unroll
    for (int m = 32; m; m >>= 1) acc += __shfl_xor(acc, m);
    __shared__ float red[16];
    if ((threadIdx.x & 63) == 0) red[threadIdx.x >> 6] = acc;
    __syncthreads();
    if (threadIdx.x == 0) {
        float tot = 0.f;
        int nw = blockDim.x >> 6;
        for (int w = 0; w < nw; ++w) tot += red[w];
        out[0] = tot / (float)N;
    }
}

// ============ PROBES: 1 GB each (2 passes over adj+tsim, fused geometry) ============
// Identical bytes; ONLY run length differs. Sized to exceed fused_k's ~165 µs so the
// top-5 replay table can't hide them. Absence from top-5 ⇒ shape ≥ ~6 TB/s.

// PA: exact phase-2 shape — 4 rows per instruction, 512B contiguous per row-visit.
__global__ __launch_bounds__(256) void p128x2_k(const float* __restrict__ adj,
                                                const float* __restrict__ tsim, int N) {
    int ib = (blockIdx.x >> 2) & 127;
    int jc = blockIdx.x & 3;
    int tid = threadIdx.x, wid = tid >> 6, lane = tid & 63;
    int l15 = lane & 15, lhi = lane >> 4;
    int i0w = ib * 64 + wid * 16;
    f32x4 s = {0, 0, 0, 0};
    for (int pass = 0; pass < 2; ++pass) {
        for (int sb = 0; sb < 8; ++sb) {
            int jsb = jc * JCHUNK + sb * 256;
#pragma unroll
            for (int rg = 0; rg < 4; ++rg) {
                int irow = rg * 4 + lhi;
                const float* ar = adj  + (size_t)(i0w + irow) * N + jsb + l15 * 8;
                const float* tr = tsim + (size_t)(i0w + irow) * N + jsb + l15 * 8;
#pragma unroll
                for (int q = 0; q < 2; ++q) {
                    f32x4 a0 = *reinterpret_cast<const f32x4*>(ar + q * 128);
                    f32x4 a1 = *reinterpret_cast<const f32x4*>(ar + q * 128 + 4);
                    f32x4 t0 = *reinterpret_cast<const f32x4*>(tr + q * 128);
                    f32x4 t1 = *reinterpret_cast<const f32x4*>(tr + q * 128 + 4);
                    s += (a0 + a1) + (t0 + t1);
                }
            }
        }
    }
    float r = s[0] + s[1] + s[2] + s[3];
    asm volatile("" :: "v"(r));
}

// PB: one row at a time — 8 KB contiguous run per row-visit (8x 1KB wave-instrs).
__global__ __launch_bounds__(256) void p1kx2_k(const float* __restrict__ adj,
                                               const float* __restrict__ tsim, int N) {
    int ib = (blockIdx.x >> 2) & 127;
    int jc = blockIdx.x & 3;
    int tid = threadIdx.x, wid = tid >> 6, lane = tid & 63;
    int i0w = ib * 64 + wid * 16;
    f32x4 s = {0, 0, 0, 0};
    for (int pass = 0; pass < 2; ++pass) {
        for (int r = 0; r < 16; ++r) {
            const float* ab = adj  + (size_t)(i0w + r) * N + jc * JCHUNK + lane * 4;
            const float* tb = tsim + (size_t)(i0w + r) * N + jc * JCHUNK + lane * 4;
#pragma unroll
            for (int k = 0; k < 8; ++k) {
                f32x4 a = *reinterpret_cast<const f32x4*>(ab + k * 256);
                f32x4 t = *reinterpret_cast<const f32x4*>(tb + k * 256);
                s += a + t;
            }
        }
    }
    float r2 = s[0] + s[1] + s[2] + s[3];
    asm volatile("" :: "v"(r2));
}

extern "C" void kernel_launch(void* const* d_in, const int* in_sizes, int n_in,
                              void* d_out, int out_size, void* d_ws, size_t ws_size,
                              hipStream_t stream) {
    const float* z    = (const float*)d_in[0];
    const float* adj  = (const float*)d_in[1];
    const float* tsim = (const float*)d_in[2];

    int N = (int)(sqrt((double)in_sizes[1]) + 0.5);  // 8192

    unsigned short* zn = (unsigned short*)d_ws;                   // 4 MB
    float* part = (float*)((char*)d_ws + (size_t)N * D_K * 2);    // 5*N f32

    normalize_k<<<N / 4, 256, 0, stream>>>(z, zn, part, N);

    int nblocks = (N >> 6) * (N / JCHUNK);  // 512
    fused_k<<<nblocks, 256, 0, stream>>>(zn, adj, tsim, part, N);

    finalize_k<<<1, 1024, 0, stream>>>(part, (float*)d_out, N);

    // ---- run-length probe pair (output-neutral; read from per-dispatch profile) ----
    p128x2_k<<<nblocks, 256, 0, stream>>>(adj, tsim, N);
    p1kx2_k <<<nblocks, 256, 0, stream>>>(adj, tsim, N);
}

// Round 19
// 162.187 us; speedup vs baseline: 3.2883x; 3.2883x over previous
//
#include <hip/hip_runtime.h>
#include <hip/hip_bf16.h>
#include <stdint.h>
#include <math.h>

typedef __attribute__((ext_vector_type(8))) short bf16x8;
typedef __attribute__((ext_vector_type(4))) float f32x4;

#define D_K 256
#define JCHUNK 2048
#define SB 256              // superblock j-width (phase alternation unit)
#define NSB (JCHUNK / SB)   // 8
#define BT 32               // MFMA subtile j-width (staged tile rows)
#define NST (SB / BT)       // 8 subtiles per superblock

__device__ __forceinline__ unsigned short f2bf(float f) {
    unsigned u = __float_as_uint(f);
    u += 0x7fffu + ((u >> 16) & 1u);   // round-to-nearest-even
    return (unsigned short)(u >> 16);
}
__device__ __forceinline__ float bf2f(unsigned short u) {
    return __uint_as_float(((unsigned)u) << 16);
}
__device__ __forceinline__ void gload_lds16(const void* g, void* l) {
    __builtin_amdgcn_global_load_lds(
        (const __attribute__((address_space(1))) void*)g,
        (__attribute__((address_space(3))) void*)l,
        16, 0, 0);
}

// ---------------- Kernel 1: row-normalize z -> bf16; zero partials ----------------
__global__ void normalize_k(const float* __restrict__ z,
                            unsigned short* __restrict__ zn,
                            float* __restrict__ part, int N) {
    int gid  = blockIdx.x * blockDim.x + threadIdx.x;
    if (gid < 5 * N) part[gid] = 0.f;      // stream-ordered before fused_k
    int gw   = gid >> 6;                   // one wave per row
    int lane = threadIdx.x & 63;
    if (gw >= N) return;
    float4 v = reinterpret_cast<const float4*>(z + (size_t)gw * D_K)[lane];
    float ss = v.x * v.x + v.y * v.y + v.z * v.z + v.w * v.w;
#pragma unroll
    for (int m = 32; m; m >>= 1) ss += __shfl_xor(ss, m);
    float sc = 1.0f / fmaxf(sqrtf(ss), 1e-8f);
    ushort4 o;
    o.x = f2bf(v.x * sc); o.y = f2bf(v.y * sc);
    o.z = f2bf(v.z * sc); o.w = f2bf(v.w * sc);
    reinterpret_cast<ushort4*>(zn + (size_t)gw * D_K)[lane] = o;
}

// Stage one 32-row x 256-d bf16 zn tile (16 KB) into LDS in [kslot][row][16B]
__device__ __forceinline__ void stage_zn(char* dst, const unsigned short* zn,
                                         int j0, int tid, int wid) {
#pragma unroll
    for (int it = 0; it < 4; ++it) {
        int li    = it * 4096 + tid * 16;
        int kslot = li >> 9;          // 0..31
        int row   = (li >> 4) & 31;   // 0..31
        const char* src = reinterpret_cast<const char*>(zn) +
                          ((size_t)(j0 + row) << 9) + (size_t)kslot * 16;
        gload_lds16(src, dst + it * 4096 + wid * 1024);
    }
}

// ---------------- Kernel 2: two-phase fused (R17 phase-1 + 1KB-run phase-2) --------
// Phase 1 (unchanged from R17, scored 164us): staged 32-j subtiles, MFMA sim,
//   exp->den, park sim bf16 in wave-private LDS [16 i][256 j] XOR-swizzled.
// Phase 2 (NEW, p1kx2 probe shape = +55% memory rate): per i-row, ONE f32x4/lane
//   = 1KB CONTIGUOUS per instruction; rows sequential; 2-deep 4-row batch
//   pipeline (named reg sets, static idx). Park read 8B/lane from row slice.
// part: [0,N) den | [N,2N) S1 | [2N,3N) A | [3N,4N) T1 | [4N,5N) T
__global__ __launch_bounds__(256, 2) void fused_k(
    const unsigned short* __restrict__ zn,
    const float* __restrict__ adj,
    const float* __restrict__ tsim,
    float* __restrict__ part, int N) {
    __shared__ alignas(128) char stageL[2][BT * 512];   // 2 x 16 KB
    __shared__ alignas(128) char parkL[4][16 * 512];    // 4 waves x 8 KB bf16 park

    const float INV_T = 1.0f / 0.07f;
    const int NIB = N >> 6;
    int ib  = (blockIdx.x >> 2) & (NIB - 1);   // slow-varying
    int jc  = blockIdx.x & 3;                  // fast-varying
    int sb0 = ib & (NSB - 1);                  // per-block superblock rotation
    int tid = threadIdx.x;
    int wid = tid >> 6, lane = tid & 63;
    int l15 = lane & 15, lhi = lane >> 4;
    int i0w = ib * 64 + wid * 16;
    int gi  = i0w + l15;
    int jb  = jc * JCHUNK;
    char* parkW = parkL[wid];

    bf16x8 bfr[8];
    {
        const bf16x8* bp = reinterpret_cast<const bf16x8*>(zn + (size_t)gi * D_K) + lhi;
#pragma unroll
        for (int ks = 0; ks < 8; ++ks) bfr[ks] = bp[ks * 4];
    }

    float accden = 0.f;
    // per-row accumulators, statically indexed (64 VGPRs)
    float rs1[16], rt1[16], ra[16], rt[16];
#pragma unroll
    for (int r = 0; r < 16; ++r) { rs1[r] = 0.f; rt1[r] = 0.f; ra[r] = 0.f; rt[r] = 0.f; }

    stage_zn(stageL[0], zn, jb + sb0 * SB, tid, wid);
    asm volatile("s_waitcnt vmcnt(0)" ::: "memory");
    __syncthreads();
    int cur = 0;

    for (int s = 0; s < NSB; ++s) {
        int sbi = (sb0 + s) & (NSB - 1);
        int jsb = jb + sbi * SB;

        // ---------- phase 1: sim for 64 i x 256 j (R17 exact) ----------
        for (int st = 0; st < NST; ++st) {
            if (st + 1 < NST) {
                stage_zn(stageL[cur ^ 1], zn, jsb + (st + 1) * BT, tid, wid);
            } else if (s + 1 < NSB) {
                int nsb = (sb0 + s + 1) & (NSB - 1);
                stage_zn(stageL[cur ^ 1], zn, jb + nsb * SB, tid, wid);
            }

            const char* buf = stageL[cur];
            f32x4 acc[2] = {(f32x4){0.f,0.f,0.f,0.f}, (f32x4){0.f,0.f,0.f,0.f}};
#pragma unroll
            for (int ks = 0; ks < 8; ++ks) {
#pragma unroll
                for (int t = 0; t < 2; ++t) {
                    int boff = (ks << 11) + (lhi << 9) + (t << 8) + (l15 << 4);
                    bf16x8 aj = *reinterpret_cast<const bf16x8*>(buf + boff);
                    acc[t] = __builtin_amdgcn_mfma_f32_16x16x32_bf16(aj, bfr[ks], acc[t], 0, 0, 0);
                }
            }
#pragma unroll
            for (int t = 0; t < 2; ++t) {
                int jcol = st * BT + t * 16 + lhi * 4;
                float sv[4];
#pragma unroll
                for (int r = 0; r < 4; ++r) {
                    sv[r] = acc[t][r] * INV_T;
                    accden += (gi == jsb + jcol + r) ? 0.f : __expf(sv[r]);
                }
                ushort4 pk;
                pk.x = f2bf(sv[0]); pk.y = f2bf(sv[1]);
                pk.z = f2bf(sv[2]); pk.w = f2bf(sv[3]);
                *reinterpret_cast<ushort4*>(
                    parkW + l15 * 512 + ((jcol * 2) ^ ((l15 & 7) << 4))) = pk;
            }
            asm volatile("s_waitcnt vmcnt(0)" ::: "memory");
            __syncthreads();
            cur ^= 1;
        }

        // ---------- phase 2: 1KB-run row streams, 2-deep 4-row batches ----------
        {
            const float* ab = adj  + (size_t)i0w * N + jsb + lane * 4;
            const float* tb = tsim + (size_t)i0w * N + jsb + lane * 4;
            f32x4 aA[4], tA[4], aB[4], tB[4];

#define LOADB(dstA, dstT, rbase)                                               \
    _Pragma("unroll")                                                          \
    for (int u = 0; u < 4; ++u) {                                              \
        dstA[u] = *reinterpret_cast<const f32x4*>(ab + (size_t)((rbase) + u) * N); \
        dstT[u] = *reinterpret_cast<const f32x4*>(tb + (size_t)((rbase) + u) * N); \
    }

#define CONSUME(rbase, srcA, srcT)                                             \
    _Pragma("unroll")                                                          \
    for (int u = 0; u < 4; ++u) {                                              \
        const int r_ = (rbase) + u;                                            \
        ushort4 s4 = *reinterpret_cast<const ushort4*>(                        \
            parkW + r_ * 512 + ((lane * 8) ^ ((r_ & 7) << 4)));                \
        float s0 = bf2f(s4.x), s1 = bf2f(s4.y), s2 = bf2f(s4.z), s3 = bf2f(s4.w); \
        rs1[r_] = fmaf(srcA[u][0], s0, fmaf(srcA[u][1], s1,                    \
                  fmaf(srcA[u][2], s2, fmaf(srcA[u][3], s3, rs1[r_]))));       \
        rt1[r_] = fmaf(srcT[u][0], s0, fmaf(srcT[u][1], s1,                    \
                  fmaf(srcT[u][2], s2, fmaf(srcT[u][3], s3, rt1[r_]))));       \
        ra[r_] += (srcA[u][0] + srcA[u][1]) + (srcA[u][2] + srcA[u][3]);       \
        rt[r_] += (srcT[u][0] + srcT[u][1]) + (srcT[u][2] + srcT[u][3]);       \
    }

            LOADB(aA, tA, 0)        // rows 0-3 in flight
            LOADB(aB, tB, 4)        // rows 4-7 in flight
            CONSUME(0, aA, tA)      // waits rows 0-3; 4-7 still flying
            LOADB(aA, tA, 8)        // rows 8-11 in flight
            CONSUME(4, aB, tB)      // waits rows 4-7; 8-11 flying
            LOADB(aB, tB, 12)       // rows 12-15 in flight
            CONSUME(8, aA, tA)
            CONSUME(12, aB, tB)
#undef LOADB
#undef CONSUME
        }
    }

    // ---------- final reductions + atomics ----------
    accden += __shfl_xor(accden, 16); accden += __shfl_xor(accden, 32);
    if (lhi == 0) atomicAdd(part + gi, accden);
#pragma unroll
    for (int r = 0; r < 16; ++r) {
        float s = rs1[r], a = ra[r], u = rt1[r], w = rt[r];
#pragma unroll
        for (int m = 1; m < 64; m <<= 1) {
            s += __shfl_xor(s, m); a += __shfl_xor(a, m);
            u += __shfl_xor(u, m); w += __shfl_xor(w, m);
        }
        if (lane == 0) {
            int gr = i0w + r;
            atomicAdd(part + (size_t)N + gr, s);
            atomicAdd(part + (size_t)2 * N + gr, a);
            atomicAdd(part + (size_t)3 * N + gr, u);
            atomicAdd(part + (size_t)4 * N + gr, w);
        }
    }
}

// ---------------- Kernel 3: finalize scalar ----------------
__global__ void finalize_k(const float* __restrict__ part, float* __restrict__ out, int N) {
    const float* den = part;
    const float* s1  = part + (size_t)N;
    const float* aa  = part + (size_t)2 * N;
    const float* t1  = part + (size_t)3 * N;
    const float* tt  = part + (size_t)4 * N;
    float acc = 0.f;
    for (int i = threadIdx.x; i < N; i += blockDim.x) {
        float ld = logf(den[i] + 1e-8f);
        acc += -(s1[i] - ld * aa[i]) / (aa[i] + 1e-8f)
               - (t1[i] - ld * tt[i]) / (tt[i] + 1e-8f);
    }
#pragma unroll
    for (int m = 32; m; m >>= 1) acc += __shfl_xor(acc, m);
    __shared__ float red[16];
    if ((threadIdx.x & 63) == 0) red[threadIdx.x >> 6] = acc;
    __syncthreads();
    if (threadIdx.x == 0) {
        float tot = 0.f;
        int nw = blockDim.x >> 6;
        for (int w = 0; w < nw; ++w) tot += red[w];
        out[0] = tot / (float)N;
    }
}

extern "C" void kernel_launch(void* const* d_in, const int* in_sizes, int n_in,
                              void* d_out, int out_size, void* d_ws, size_t ws_size,
                              hipStream_t stream) {
    const float* z    = (const float*)d_in[0];
    const float* adj  = (const float*)d_in[1];
    const float* tsim = (const float*)d_in[2];

    int N = (int)(sqrt((double)in_sizes[1]) + 0.5);  // 8192

    unsigned short* zn = (unsigned short*)d_ws;                   // 4 MB
    float* part = (float*)((char*)d_ws + (size_t)N * D_K * 2);    // 5*N f32

    normalize_k<<<N / 4, 256, 0, stream>>>(z, zn, part, N);

    int nblocks = (N >> 6) * (N / JCHUNK);  // 512
    fused_k<<<nblocks, 256, 0, stream>>>(zn, adj, tsim, part, N);

    finalize_k<<<1, 1024, 0, stream>>>(part, (float*)d_out, N);
}